// Round 1
// baseline (965.444 us; speedup 1.0000x reference)
//
#include <hip/hip_runtime.h>
#include <math.h>

#define NNODES 50000
#define NEDGES 800000
#define HD     128      // H*D
#define NHEADS 4
#define DH     32
#define SCAN_T 1024

static __device__ __forceinline__ float lrelu(float x){ return x > 0.f ? x : 0.2f*x; }
static __device__ __forceinline__ float elu(float x){ return x > 0.f ? x : __expf(x) - 1.f; }

// ---------------- CSR build ----------------

__global__ void zero_kernel(int* a, int* b, int n){
  int i = blockIdx.x*blockDim.x + threadIdx.x;
  if (i < n){ a[i] = 0; b[i] = 0; }
}

__global__ void count_kernel(const int* __restrict__ dst, int* deg, int e){
  int i = blockIdx.x*blockDim.x + threadIdx.x;
  if (i < e) atomicAdd(&deg[dst[i]], 1);
}

__global__ void scan1_kernel(const int* __restrict__ deg, int* rowptr, int* bsum, int n){
  __shared__ int tmp[SCAN_T];
  int i = blockIdx.x*SCAN_T + threadIdx.x;
  int x = (i < n) ? deg[i] : 0;
  tmp[threadIdx.x] = x;
  __syncthreads();
  for (int off = 1; off < SCAN_T; off <<= 1){
    int v = (threadIdx.x >= off) ? tmp[threadIdx.x - off] : 0;
    __syncthreads();
    tmp[threadIdx.x] += v;
    __syncthreads();
  }
  if (i < n) rowptr[i] = tmp[threadIdx.x] - x;      // exclusive within block
  if (threadIdx.x == SCAN_T-1) bsum[blockIdx.x] = tmp[SCAN_T-1];
}

__global__ void scan2_kernel(int* bsum, int* rowptr, int nb, int n, int e){
  if (blockIdx.x == 0 && threadIdx.x == 0){
    int run = 0;
    for (int b = 0; b < nb; b++){ int t = bsum[b]; bsum[b] = run; run += t; }
    rowptr[n] = e;
  }
}

__global__ void scan3_kernel(int* rowptr, const int* __restrict__ bsum, int n){
  int i = blockIdx.x*SCAN_T + threadIdx.x;
  if (i < n) rowptr[i] += bsum[blockIdx.x];
}

__global__ void fill_kernel(const int* __restrict__ src, const int* __restrict__ dst,
                            const int* __restrict__ rowptr, int* wcur, int* srcs, int e){
  int i = blockIdx.x*blockDim.x + threadIdx.x;
  if (i >= e) return;
  int d = dst[i];
  int p = atomicAdd(&wcur[d], 1);
  srcs[rowptr[d] + p] = src[i];
}

// ---------------- GEMM (h @ W) + el/er epilogue ----------------
// block = 256 threads = 8 rows x 32 lane-groups; each thread computes 4 contiguous cols.
__global__ __launch_bounds__(256) void gemm_feat_kernel(
    const float* __restrict__ h, int hstride,
    const float* __restrict__ W, const float* __restrict__ al, const float* __restrict__ ar,
    float* __restrict__ feat, float* __restrict__ elv, float* __restrict__ erv)
{
  int t = threadIdx.x;
  int lane = t & 31;
  int r = t >> 5;
  int n = blockIdx.x*8 + r;                 // N divisible by 8 (50000/8 = 6250)
  const float* hrow = h + (size_t)n*hstride;
  int j = lane*4;
  float ax = 0.f, ay = 0.f, az = 0.f, aw = 0.f;
  #pragma unroll 4
  for (int k = 0; k < HD; k += 4){
    float4 h4 = *(const float4*)(hrow + k);
    const float* wp = W + k*HD + j;
    float4 w0 = *(const float4*)(wp);
    float4 w1 = *(const float4*)(wp + HD);
    float4 w2 = *(const float4*)(wp + 2*HD);
    float4 w3 = *(const float4*)(wp + 3*HD);
    ax += h4.x*w0.x + h4.y*w1.x + h4.z*w2.x + h4.w*w3.x;
    ay += h4.x*w0.y + h4.y*w1.y + h4.z*w2.y + h4.w*w3.y;
    az += h4.x*w0.z + h4.y*w1.z + h4.z*w2.z + h4.w*w3.z;
    aw += h4.x*w0.w + h4.y*w1.w + h4.z*w2.w + h4.w*w3.w;
  }
  // epilogue: el = feat . al (per head), reduce over the 8 lanes that share a head
  int head = lane >> 3;
  int dpos = j & 31;
  float4 al4 = *(const float4*)(al + head*DH + dpos);
  float4 ar4 = *(const float4*)(ar + head*DH + dpos);
  float pl = ax*al4.x + ay*al4.y + az*al4.z + aw*al4.w;
  float pr = ax*ar4.x + ay*ar4.y + az*ar4.z + aw*ar4.w;
  pl += __shfl_xor(pl, 1); pl += __shfl_xor(pl, 2); pl += __shfl_xor(pl, 4);
  pr += __shfl_xor(pr, 1); pr += __shfl_xor(pr, 2); pr += __shfl_xor(pr, 4);
  float4 o; o.x = ax; o.y = ay; o.z = az; o.w = aw;
  *(float4*)(feat + (size_t)n*HD + j) = o;
  if ((lane & 7) == 0){ elv[n*NHEADS + head] = pl; erv[n*NHEADS + head] = pr; }
}

// ---------------- edge softmax (per dst node, thread/node) ----------------
__global__ void softmax_kernel(const int* __restrict__ rowptr, const int* __restrict__ srcs,
                               const float* __restrict__ elv, const float* __restrict__ erv,
                               float* __restrict__ a_sorted, float* __restrict__ ssum, int n)
{
  int nd = blockIdx.x*blockDim.x + threadIdx.x;
  if (nd >= n) return;
  int s0 = rowptr[nd], s1 = rowptr[nd+1];
  float4 er4 = *(const float4*)(erv + nd*4);
  float mx = -3.4e38f, my = -3.4e38f, mz = -3.4e38f, mw = -3.4e38f;
  for (int i = s0; i < s1; i++){
    int s = srcs[i];
    float4 el4 = *(const float4*)(elv + s*4);
    float ex = lrelu(el4.x + er4.x), ey = lrelu(el4.y + er4.y);
    float ez = lrelu(el4.z + er4.z), ew = lrelu(el4.w + er4.w);
    mx = fmaxf(mx, ex); my = fmaxf(my, ey); mz = fmaxf(mz, ez); mw = fmaxf(mw, ew);
  }
  float sx = 0.f, sy = 0.f, sz = 0.f, sw = 0.f;
  for (int i = s0; i < s1; i++){
    int s = srcs[i];
    float4 el4 = *(const float4*)(elv + s*4);
    float4 ex;
    ex.x = __expf(lrelu(el4.x + er4.x) - mx);
    ex.y = __expf(lrelu(el4.y + er4.y) - my);
    ex.z = __expf(lrelu(el4.z + er4.z) - mz);
    ex.w = __expf(lrelu(el4.w + er4.w) - mw);
    *(float4*)(a_sorted + (size_t)i*4) = ex;
    sx += ex.x; sy += ex.y; sz += ex.z; sw += ex.w;
  }
  float4 sv; sv.x = sx; sv.y = sy; sv.z = sz; sv.w = sw;
  *(float4*)(ssum + nd*4) = sv;
}

// ---------------- aggregation (wave per dst node, lane = feature) ----------------
__global__ __launch_bounds__(256) void agg_kernel(
    const int* __restrict__ rowptr, const int* __restrict__ srcs,
    const float* __restrict__ a_sorted, const float* __restrict__ feat,
    const float* __restrict__ ssum, float* __restrict__ emb_out, int n)
{
  int wid  = (int)((blockIdx.x*(size_t)blockDim.x + threadIdx.x) >> 6);
  int lane = threadIdx.x & 63;
  if (wid >= n) return;
  int s0 = rowptr[wid], s1 = rowptr[wid+1];
  int h1 = lane >> 5;                       // head for feature `lane` (0/1); +2 for lane+64
  float acc0 = 0.f, acc1 = 0.f;
  for (int i = s0; i < s1; i++){
    int s = srcs[i];
    float4 a4 = *(const float4*)(a_sorted + (size_t)i*4);
    float aA = (h1 == 0) ? a4.x : a4.y;
    float aB = (h1 == 0) ? a4.z : a4.w;
    const float* fr = feat + (size_t)s*HD;
    acc0 += fr[lane]      * aA;
    acc1 += fr[64 + lane] * aB;
  }
  float4 sv = *(const float4*)(ssum + wid*4);
  float sA = (h1 == 0) ? sv.x : sv.y;
  float sB = (h1 == 0) ? sv.z : sv.w;
  float o0 = (s1 > s0) ? elu(acc0 / sA) : 0.f;
  float o1 = (s1 > s0) ? elu(acc1 / sB) : 0.f;
  emb_out[(size_t)wid*384 + lane]      = o0;   // emb_out pre-offset by layer*128
  emb_out[(size_t)wid*384 + 64 + lane] = o1;
}

// ---------------- final projection: emb[N,384] @ Wproj[384,32] ----------------
__global__ __launch_bounds__(256) void proj_kernel(
    const float* __restrict__ emb, const float* __restrict__ Wp, float* __restrict__ out)
{
  __shared__ float wlds[384*32];            // 48 KB
  int t = threadIdx.x;
  for (int i = t; i < 384*32; i += 256) wlds[i] = Wp[i];
  __syncthreads();
  int c = t & 31, r = t >> 5;
  int n = blockIdx.x*8 + r;
  const float* erow = emb + (size_t)n*384;
  float acc = 0.f;
  #pragma unroll 4
  for (int k = 0; k < 384; k += 4){
    float4 e4 = *(const float4*)(erow + k);
    acc += e4.x*wlds[k*32 + c] + e4.y*wlds[(k+1)*32 + c]
         + e4.z*wlds[(k+2)*32 + c] + e4.w*wlds[(k+3)*32 + c];
  }
  out[(size_t)n*32 + c] = acc;
}

// ---------------- launch ----------------
extern "C" void kernel_launch(void* const* d_in, const int* in_sizes, int n_in,
                              void* d_out, int out_size, void* d_ws, size_t ws_size,
                              hipStream_t stream) {
  const float* x    = (const float*)d_in[0];
  const int*   src  = (const int*)d_in[1];
  const int*   dst  = (const int*)d_in[2];
  const float* Ws[3]  = { (const float*)d_in[3], (const float*)d_in[6], (const float*)d_in[9]  };
  const float* als[3] = { (const float*)d_in[4], (const float*)d_in[7], (const float*)d_in[10] };
  const float* ars[3] = { (const float*)d_in[5], (const float*)d_in[8], (const float*)d_in[11] };
  const float* Wproj  = (const float*)d_in[12];
  float* out = (float*)d_out;

  char* wptr = (char*)d_ws;
  auto alloc = [&](size_t bytes) -> void* {
    void* p = (void*)wptr; wptr += (bytes + 255) & ~(size_t)255; return p;
  };
  int*   deg        = (int*)  alloc((size_t)NNODES*4);
  int*   wcur       = (int*)  alloc((size_t)NNODES*4);
  int*   rowptr     = (int*)  alloc((size_t)(NNODES+1)*4);
  int*   bsum       = (int*)  alloc(256*4);
  int*   src_sorted = (int*)  alloc((size_t)NEDGES*4);
  float* feat       = (float*)alloc((size_t)NNODES*HD*4);
  float* elv        = (float*)alloc((size_t)NNODES*NHEADS*4);
  float* erv        = (float*)alloc((size_t)NNODES*NHEADS*4);
  float* ssum       = (float*)alloc((size_t)NNODES*NHEADS*4);
  float* a_sorted   = (float*)alloc((size_t)NEDGES*NHEADS*4);
  float* emb        = (float*)alloc((size_t)NNODES*384*4);

  const int NB_SCAN = (NNODES + SCAN_T - 1) / SCAN_T;   // 49

  zero_kernel<<<(NNODES+255)/256, 256, 0, stream>>>(deg, wcur, NNODES);
  count_kernel<<<(NEDGES+255)/256, 256, 0, stream>>>(dst, deg, NEDGES);
  scan1_kernel<<<NB_SCAN, SCAN_T, 0, stream>>>(deg, rowptr, bsum, NNODES);
  scan2_kernel<<<1, 64, 0, stream>>>(bsum, rowptr, NB_SCAN, NNODES, NEDGES);
  scan3_kernel<<<NB_SCAN, SCAN_T, 0, stream>>>(rowptr, bsum, NNODES);
  fill_kernel<<<(NEDGES+255)/256, 256, 0, stream>>>(src, dst, rowptr, wcur, src_sorted, NEDGES);

  const float* hin = x;
  int hstride = 128;
  for (int l = 0; l < 3; l++){
    gemm_feat_kernel<<<NNODES/8, 256, 0, stream>>>(hin, hstride, Ws[l], als[l], ars[l],
                                                   feat, elv, erv);
    softmax_kernel<<<(NNODES+255)/256, 256, 0, stream>>>(rowptr, src_sorted, elv, erv,
                                                         a_sorted, ssum, NNODES);
    agg_kernel<<<(NNODES*64+255)/256, 256, 0, stream>>>(rowptr, src_sorted, a_sorted, feat,
                                                        ssum, emb + (size_t)l*128, NNODES);
    hin = emb + (size_t)l*128;   // output of layer l feeds layer l+1
    hstride = 384;
  }

  proj_kernel<<<NNODES/8, 256, 0, stream>>>(emb, Wproj, out);
}

// Round 3
// 709.952 us; speedup vs baseline: 1.3599x; 1.3599x over previous
//
#include <hip/hip_runtime.h>
#include <math.h>

#define NNODES 50000
#define NEDGES 800000
#define HD     128      // H*D
#define NHEADS 4
#define DH     32
#define SCAN_T 1024

#define TILE_R 64       // gemm rows per block
#define KCH    32       // k-chunk
#define AP     36       // padded A-tile k-stride (36*4B=144B, 16B-aligned, 2-way-bank=free)

static __device__ __forceinline__ float lrelu(float x){ return x > 0.f ? x : 0.2f*x; }
static __device__ __forceinline__ float elu(float x){ return x > 0.f ? x : __expf(x) - 1.f; }

// ---------------- CSR build ----------------

__global__ void zero_kernel(int* a, int* b, int n){
  int i = blockIdx.x*blockDim.x + threadIdx.x;
  if (i < n){ a[i] = 0; b[i] = 0; }
}

__global__ void count_kernel(const int* __restrict__ dst, int* deg, int e){
  int i = blockIdx.x*blockDim.x + threadIdx.x;
  if (i < e) atomicAdd(&deg[dst[i]], 1);
}

__global__ void scan1_kernel(const int* __restrict__ deg, int* rowptr, int* bsum, int n){
  __shared__ int tmp[SCAN_T];
  int i = blockIdx.x*SCAN_T + threadIdx.x;
  int x = (i < n) ? deg[i] : 0;
  tmp[threadIdx.x] = x;
  __syncthreads();
  for (int off = 1; off < SCAN_T; off <<= 1){
    int v = (threadIdx.x >= off) ? tmp[threadIdx.x - off] : 0;
    __syncthreads();
    tmp[threadIdx.x] += v;
    __syncthreads();
  }
  if (i < n) rowptr[i] = tmp[threadIdx.x] - x;      // exclusive within block
  if (threadIdx.x == SCAN_T-1) bsum[blockIdx.x] = tmp[SCAN_T-1];
}

__global__ void scan2_kernel(int* bsum, int* rowptr, int nb, int n, int e){
  if (blockIdx.x == 0 && threadIdx.x == 0){
    int run = 0;
    for (int b = 0; b < nb; b++){ int t = bsum[b]; bsum[b] = run; run += t; }
    rowptr[n] = e;
  }
}

__global__ void scan3_kernel(int* rowptr, const int* __restrict__ bsum, int n){
  int i = blockIdx.x*SCAN_T + threadIdx.x;
  if (i < n) rowptr[i] += bsum[blockIdx.x];
}

__global__ void fill_kernel(const int* __restrict__ src, const int* __restrict__ dst,
                            const int* __restrict__ rowptr, int* wcur, int* srcs, int e){
  int i = blockIdx.x*blockDim.x + threadIdx.x;
  if (i >= e) return;
  int d = dst[i];
  int p = atomicAdd(&wcur[d], 1);
  srcs[rowptr[d] + p] = src[i];
}

// ---------------- GEMM (h @ W) + el/er epilogue ----------------
// 64-row x 128-col tile; LDS-staged A chunk (64x32, padded) + W chunk (32x128).
// 256 threads: tx=t&15 owns cols tx*8..+8, ty=t>>4 owns rows ty*4..+4.
// NOTE: W chunk is 4096 floats; 256 threads must stage 16 floats EACH
// (flat offsets t*8 and 2048+t*8) — staging only t*8 covers half the chunk
// and leaves k=16..31 uninitialized (round-2 NaN bug).
__global__ __launch_bounds__(256) void gemm_feat_kernel(
    const float* __restrict__ h, int hstride,
    const float* __restrict__ W, const float* __restrict__ al, const float* __restrict__ ar,
    float* __restrict__ feat, float* __restrict__ elv, float* __restrict__ erv)
{
  __shared__ float As[TILE_R*AP];   // 9216 B
  __shared__ float Ws[KCH*HD];      // 16384 B
  int t = threadIdx.x;
  int tx = t & 15, ty = t >> 4;
  int rbase = blockIdx.x * TILE_R;

  float acc[4][8];
  #pragma unroll
  for (int r = 0; r < 4; r++)
    #pragma unroll
    for (int j = 0; j < 8; j++) acc[r][j] = 0.f;

  int arow = t >> 2;            // staging: row 0..63
  int akk  = (t & 3) * 8;       // staging: k-offset 0..31 (2 float4)
  int an   = rbase + arow;
  const float* ap = h + (size_t)an*hstride + akk;

  for (int kb = 0; kb < HD; kb += KCH){
    float4 v0, v1;
    if (an < NNODES){
      v0 = *(const float4*)(ap + kb);
      v1 = *(const float4*)(ap + kb + 4);
    } else {
      v0 = make_float4(0.f,0.f,0.f,0.f);
      v1 = v0;
    }
    *(float4*)&As[arow*AP + akk]     = v0;
    *(float4*)&As[arow*AP + akk + 4] = v1;
    // flat-copy the full 4096-float W chunk: 16 floats per thread
    const float* wp = W + (size_t)kb*HD;
    *(float4*)&Ws[t*8]          = *(const float4*)(wp + t*8);
    *(float4*)&Ws[t*8 + 4]      = *(const float4*)(wp + t*8 + 4);
    *(float4*)&Ws[2048 + t*8]     = *(const float4*)(wp + 2048 + t*8);
    *(float4*)&Ws[2048 + t*8 + 4] = *(const float4*)(wp + 2048 + t*8 + 4);
    __syncthreads();

    #pragma unroll 4
    for (int k = 0; k < KCH; k++){
      float4 b0 = *(const float4*)&Ws[k*HD + tx*8];
      float4 b1 = *(const float4*)&Ws[k*HD + tx*8 + 4];
      #pragma unroll
      for (int r = 0; r < 4; r++){
        float a = As[(ty*4 + r)*AP + k];
        acc[r][0] += a*b0.x; acc[r][1] += a*b0.y;
        acc[r][2] += a*b0.z; acc[r][3] += a*b0.w;
        acc[r][4] += a*b1.x; acc[r][5] += a*b1.y;
        acc[r][6] += a*b1.z; acc[r][7] += a*b1.w;
      }
    }
    __syncthreads();
  }

  // epilogue: el/er. cols tx*8..+8 live in head = tx>>2, d-offset (tx&3)*8.
  int head  = tx >> 2;
  int dbase = (tx & 3) * 8;
  float4 al0 = *(const float4*)(al + head*DH + dbase);
  float4 al1 = *(const float4*)(al + head*DH + dbase + 4);
  float4 ar0 = *(const float4*)(ar + head*DH + dbase);
  float4 ar1 = *(const float4*)(ar + head*DH + dbase + 4);

  #pragma unroll
  for (int r = 0; r < 4; r++){
    int n = rbase + ty*4 + r;
    float pl = acc[r][0]*al0.x + acc[r][1]*al0.y + acc[r][2]*al0.z + acc[r][3]*al0.w
             + acc[r][4]*al1.x + acc[r][5]*al1.y + acc[r][6]*al1.z + acc[r][7]*al1.w;
    float pr = acc[r][0]*ar0.x + acc[r][1]*ar0.y + acc[r][2]*ar0.z + acc[r][3]*ar0.w
             + acc[r][4]*ar1.x + acc[r][5]*ar1.y + acc[r][6]*ar1.z + acc[r][7]*ar1.w;
    pl += __shfl_xor(pl, 1); pl += __shfl_xor(pl, 2);
    pr += __shfl_xor(pr, 1); pr += __shfl_xor(pr, 2);
    if (n < NNODES){
      float4 o0 = make_float4(acc[r][0], acc[r][1], acc[r][2], acc[r][3]);
      float4 o1 = make_float4(acc[r][4], acc[r][5], acc[r][6], acc[r][7]);
      *(float4*)(feat + (size_t)n*HD + tx*8)     = o0;
      *(float4*)(feat + (size_t)n*HD + tx*8 + 4) = o1;
      if ((tx & 3) == 0){
        elv[n*NHEADS + head] = pl;
        erv[n*NHEADS + head] = pr;
      }
    }
  }
}

// ---------------- edge softmax (per dst node, thread/node) ----------------
__global__ void softmax_kernel(const int* __restrict__ rowptr, const int* __restrict__ srcs,
                               const float* __restrict__ elv, const float* __restrict__ erv,
                               float* __restrict__ a_sorted, float* __restrict__ ssum, int n)
{
  int nd = blockIdx.x*blockDim.x + threadIdx.x;
  if (nd >= n) return;
  int s0 = rowptr[nd], s1 = rowptr[nd+1];
  float4 er4 = *(const float4*)(erv + nd*4);
  float mx = -3.4e38f, my = -3.4e38f, mz = -3.4e38f, mw = -3.4e38f;
  for (int i = s0; i < s1; i++){
    int s = srcs[i];
    float4 el4 = *(const float4*)(elv + s*4);
    float ex = lrelu(el4.x + er4.x), ey = lrelu(el4.y + er4.y);
    float ez = lrelu(el4.z + er4.z), ew = lrelu(el4.w + er4.w);
    mx = fmaxf(mx, ex); my = fmaxf(my, ey); mz = fmaxf(mz, ez); mw = fmaxf(mw, ew);
  }
  float sx = 0.f, sy = 0.f, sz = 0.f, sw = 0.f;
  for (int i = s0; i < s1; i++){
    int s = srcs[i];
    float4 el4 = *(const float4*)(elv + s*4);
    float4 ex;
    ex.x = __expf(lrelu(el4.x + er4.x) - mx);
    ex.y = __expf(lrelu(el4.y + er4.y) - my);
    ex.z = __expf(lrelu(el4.z + er4.z) - mz);
    ex.w = __expf(lrelu(el4.w + er4.w) - mw);
    *(float4*)(a_sorted + (size_t)i*4) = ex;
    sx += ex.x; sy += ex.y; sz += ex.z; sw += ex.w;
  }
  float4 sv; sv.x = sx; sv.y = sy; sv.z = sz; sv.w = sw;
  *(float4*)(ssum + nd*4) = sv;
}

// ---------------- aggregation (wave per dst node, lane = feature) ----------------
__global__ __launch_bounds__(256) void agg_kernel(
    const int* __restrict__ rowptr, const int* __restrict__ srcs,
    const float* __restrict__ a_sorted, const float* __restrict__ feat,
    const float* __restrict__ ssum, float* __restrict__ emb_out, int n)
{
  int wid  = (int)((blockIdx.x*(size_t)blockDim.x + threadIdx.x) >> 6);
  int lane = threadIdx.x & 63;
  if (wid >= n) return;
  int s0 = rowptr[wid], s1 = rowptr[wid+1];
  int h1 = lane >> 5;                       // head for feature `lane` (0/1); +2 for lane+64
  float acc0 = 0.f, acc1 = 0.f;
  for (int i = s0; i < s1; i++){
    int s = srcs[i];
    float4 a4 = *(const float4*)(a_sorted + (size_t)i*4);
    float aA = (h1 == 0) ? a4.x : a4.y;
    float aB = (h1 == 0) ? a4.z : a4.w;
    const float* fr = feat + (size_t)s*HD;
    acc0 += fr[lane]      * aA;
    acc1 += fr[64 + lane] * aB;
  }
  float4 sv = *(const float4*)(ssum + wid*4);
  float sA = (h1 == 0) ? sv.x : sv.y;
  float sB = (h1 == 0) ? sv.z : sv.w;
  float o0 = (s1 > s0) ? elu(acc0 / sA) : 0.f;
  float o1 = (s1 > s0) ? elu(acc1 / sB) : 0.f;
  emb_out[(size_t)wid*384 + lane]      = o0;   // emb_out pre-offset by layer*128
  emb_out[(size_t)wid*384 + 64 + lane] = o1;
}

// ---------------- final projection: emb[N,384] @ Wproj[384,32] ----------------
__global__ __launch_bounds__(256) void proj_kernel(
    const float* __restrict__ emb, const float* __restrict__ Wp, float* __restrict__ out)
{
  __shared__ float wlds[384*32];            // 48 KB
  int t = threadIdx.x;
  for (int i = t; i < 384*32; i += 256) wlds[i] = Wp[i];
  __syncthreads();
  int c = t & 31, r = t >> 5;
  int n = blockIdx.x*8 + r;
  const float* erow = emb + (size_t)n*384;
  float acc = 0.f;
  #pragma unroll 4
  for (int k = 0; k < 384; k += 4){
    float4 e4 = *(const float4*)(erow + k);
    acc += e4.x*wlds[k*32 + c] + e4.y*wlds[(k+1)*32 + c]
         + e4.z*wlds[(k+2)*32 + c] + e4.w*wlds[(k+3)*32 + c];
  }
  out[(size_t)n*32 + c] = acc;
}

// ---------------- launch ----------------
extern "C" void kernel_launch(void* const* d_in, const int* in_sizes, int n_in,
                              void* d_out, int out_size, void* d_ws, size_t ws_size,
                              hipStream_t stream) {
  const float* x    = (const float*)d_in[0];
  const int*   src  = (const int*)d_in[1];
  const int*   dst  = (const int*)d_in[2];
  const float* Ws_[3]  = { (const float*)d_in[3], (const float*)d_in[6], (const float*)d_in[9]  };
  const float* als[3] = { (const float*)d_in[4], (const float*)d_in[7], (const float*)d_in[10] };
  const float* ars[3] = { (const float*)d_in[5], (const float*)d_in[8], (const float*)d_in[11] };
  const float* Wproj  = (const float*)d_in[12];
  float* out = (float*)d_out;

  char* wptr = (char*)d_ws;
  auto alloc = [&](size_t bytes) -> void* {
    void* p = (void*)wptr; wptr += (bytes + 255) & ~(size_t)255; return p;
  };
  int*   deg        = (int*)  alloc((size_t)NNODES*4);
  int*   wcur       = (int*)  alloc((size_t)NNODES*4);
  int*   rowptr     = (int*)  alloc((size_t)(NNODES+1)*4);
  int*   bsum       = (int*)  alloc(256*4);
  int*   src_sorted = (int*)  alloc((size_t)NEDGES*4);
  float* feat       = (float*)alloc((size_t)NNODES*HD*4);
  float* elv        = (float*)alloc((size_t)NNODES*NHEADS*4);
  float* erv        = (float*)alloc((size_t)NNODES*NHEADS*4);
  float* ssum       = (float*)alloc((size_t)NNODES*NHEADS*4);
  float* a_sorted   = (float*)alloc((size_t)NEDGES*NHEADS*4);
  float* emb        = (float*)alloc((size_t)NNODES*384*4);

  const int NB_SCAN = (NNODES + SCAN_T - 1) / SCAN_T;   // 49

  zero_kernel<<<(NNODES+255)/256, 256, 0, stream>>>(deg, wcur, NNODES);
  count_kernel<<<(NEDGES+255)/256, 256, 0, stream>>>(dst, deg, NEDGES);
  scan1_kernel<<<NB_SCAN, SCAN_T, 0, stream>>>(deg, rowptr, bsum, NNODES);
  scan2_kernel<<<1, 64, 0, stream>>>(bsum, rowptr, NB_SCAN, NNODES, NEDGES);
  scan3_kernel<<<NB_SCAN, SCAN_T, 0, stream>>>(rowptr, bsum, NNODES);
  fill_kernel<<<(NEDGES+255)/256, 256, 0, stream>>>(src, dst, rowptr, wcur, src_sorted, NEDGES);

  const float* hin = x;
  int hstride = 128;
  for (int l = 0; l < 3; l++){
    gemm_feat_kernel<<<(NNODES + TILE_R - 1)/TILE_R, 256, 0, stream>>>(
        hin, hstride, Ws_[l], als[l], ars[l], feat, elv, erv);
    softmax_kernel<<<(NNODES+255)/256, 256, 0, stream>>>(rowptr, src_sorted, elv, erv,
                                                         a_sorted, ssum, NNODES);
    agg_kernel<<<(NNODES*64+255)/256, 256, 0, stream>>>(rowptr, src_sorted, a_sorted, feat,
                                                        ssum, emb + (size_t)l*128, NNODES);
    hin = emb + (size_t)l*128;   // output of layer l feeds layer l+1
    hstride = 384;
  }

  proj_kernel<<<NNODES/8, 256, 0, stream>>>(emb, Wproj, out);
}

// Round 4
// 664.468 us; speedup vs baseline: 1.4530x; 1.0685x over previous
//
#include <hip/hip_runtime.h>
#include <math.h>

#define NNODES 50000
#define NEDGES 800000
#define HD     128      // H*D
#define NHEADS 4
#define DH     32
#define SCAN_T 1024

#define TILE_R 64       // gemm rows per block
#define KCH    32       // k-chunk
#define AP     36       // padded A-tile k-stride (36*4B=144B, 16B-aligned, 2-way-bank=free)

#define PTILE  128      // proj rows per block

static __device__ __forceinline__ float lrelu(float x){ return x > 0.f ? x : 0.2f*x; }
static __device__ __forceinline__ float elu(float x){ return x > 0.f ? x : __expf(x) - 1.f; }

// ---------------- CSR build ----------------

__global__ void zero_kernel(int* a, int* b, int n){
  int i = blockIdx.x*blockDim.x + threadIdx.x;
  if (i < n){ a[i] = 0; b[i] = 0; }
}

__global__ void count_kernel(const int* __restrict__ dst, int* deg, int e){
  int i = blockIdx.x*blockDim.x + threadIdx.x;
  if (i < e) atomicAdd(&deg[dst[i]], 1);
}

__global__ void scan1_kernel(const int* __restrict__ deg, int* rowptr, int* bsum, int n){
  __shared__ int tmp[SCAN_T];
  int i = blockIdx.x*SCAN_T + threadIdx.x;
  int x = (i < n) ? deg[i] : 0;
  tmp[threadIdx.x] = x;
  __syncthreads();
  for (int off = 1; off < SCAN_T; off <<= 1){
    int v = (threadIdx.x >= off) ? tmp[threadIdx.x - off] : 0;
    __syncthreads();
    tmp[threadIdx.x] += v;
    __syncthreads();
  }
  if (i < n) rowptr[i] = tmp[threadIdx.x] - x;      // exclusive within block
  if (threadIdx.x == SCAN_T-1) bsum[blockIdx.x] = tmp[SCAN_T-1];
}

__global__ void scan2_kernel(int* bsum, int* rowptr, int nb, int n, int e){
  if (blockIdx.x == 0 && threadIdx.x == 0){
    int run = 0;
    for (int b = 0; b < nb; b++){ int t = bsum[b]; bsum[b] = run; run += t; }
    rowptr[n] = e;
  }
}

__global__ void scan3_kernel(int* rowptr, const int* __restrict__ bsum, int n){
  int i = blockIdx.x*SCAN_T + threadIdx.x;
  if (i < n) rowptr[i] += bsum[blockIdx.x];
}

__global__ void fill_kernel(const int* __restrict__ src, const int* __restrict__ dst,
                            const int* __restrict__ rowptr, int* wcur, int* srcs, int e){
  int i = blockIdx.x*blockDim.x + threadIdx.x;
  if (i >= e) return;
  int d = dst[i];
  int p = atomicAdd(&wcur[d], 1);
  srcs[rowptr[d] + p] = src[i];
}

// ---------------- GEMM (h @ W) + el/er epilogue ----------------
__global__ __launch_bounds__(256) void gemm_feat_kernel(
    const float* __restrict__ h, int hstride,
    const float* __restrict__ W, const float* __restrict__ al, const float* __restrict__ ar,
    float* __restrict__ feat, float* __restrict__ elv, float* __restrict__ erv)
{
  __shared__ float As[TILE_R*AP];   // 9216 B
  __shared__ float Ws[KCH*HD];      // 16384 B
  int t = threadIdx.x;
  int tx = t & 15, ty = t >> 4;
  int rbase = blockIdx.x * TILE_R;

  float acc[4][8];
  #pragma unroll
  for (int r = 0; r < 4; r++)
    #pragma unroll
    for (int j = 0; j < 8; j++) acc[r][j] = 0.f;

  int arow = t >> 2;            // staging: row 0..63
  int akk  = (t & 3) * 8;       // staging: k-offset 0..31 (2 float4)
  int an   = rbase + arow;
  const float* ap = h + (size_t)an*hstride + akk;

  for (int kb = 0; kb < HD; kb += KCH){
    float4 v0, v1;
    if (an < NNODES){
      v0 = *(const float4*)(ap + kb);
      v1 = *(const float4*)(ap + kb + 4);
    } else {
      v0 = make_float4(0.f,0.f,0.f,0.f);
      v1 = v0;
    }
    *(float4*)&As[arow*AP + akk]     = v0;
    *(float4*)&As[arow*AP + akk + 4] = v1;
    // flat-copy the full 4096-float W chunk: 16 floats per thread
    const float* wp = W + (size_t)kb*HD;
    *(float4*)&Ws[t*8]          = *(const float4*)(wp + t*8);
    *(float4*)&Ws[t*8 + 4]      = *(const float4*)(wp + t*8 + 4);
    *(float4*)&Ws[2048 + t*8]     = *(const float4*)(wp + 2048 + t*8);
    *(float4*)&Ws[2048 + t*8 + 4] = *(const float4*)(wp + 2048 + t*8 + 4);
    __syncthreads();

    #pragma unroll 4
    for (int k = 0; k < KCH; k++){
      float4 b0 = *(const float4*)&Ws[k*HD + tx*8];
      float4 b1 = *(const float4*)&Ws[k*HD + tx*8 + 4];
      #pragma unroll
      for (int r = 0; r < 4; r++){
        float a = As[(ty*4 + r)*AP + k];
        acc[r][0] += a*b0.x; acc[r][1] += a*b0.y;
        acc[r][2] += a*b0.z; acc[r][3] += a*b0.w;
        acc[r][4] += a*b1.x; acc[r][5] += a*b1.y;
        acc[r][6] += a*b1.z; acc[r][7] += a*b1.w;
      }
    }
    __syncthreads();
  }

  // epilogue: el/er. cols tx*8..+8 live in head = tx>>2, d-offset (tx&3)*8.
  int head  = tx >> 2;
  int dbase = (tx & 3) * 8;
  float4 al0 = *(const float4*)(al + head*DH + dbase);
  float4 al1 = *(const float4*)(al + head*DH + dbase + 4);
  float4 ar0 = *(const float4*)(ar + head*DH + dbase);
  float4 ar1 = *(const float4*)(ar + head*DH + dbase + 4);

  #pragma unroll
  for (int r = 0; r < 4; r++){
    int n = rbase + ty*4 + r;
    float pl = acc[r][0]*al0.x + acc[r][1]*al0.y + acc[r][2]*al0.z + acc[r][3]*al0.w
             + acc[r][4]*al1.x + acc[r][5]*al1.y + acc[r][6]*al1.z + acc[r][7]*al1.w;
    float pr = acc[r][0]*ar0.x + acc[r][1]*ar0.y + acc[r][2]*ar0.z + acc[r][3]*ar0.w
             + acc[r][4]*ar1.x + acc[r][5]*ar1.y + acc[r][6]*ar1.z + acc[r][7]*ar1.w;
    pl += __shfl_xor(pl, 1); pl += __shfl_xor(pl, 2);
    pr += __shfl_xor(pr, 1); pr += __shfl_xor(pr, 2);
    if (n < NNODES){
      float4 o0 = make_float4(acc[r][0], acc[r][1], acc[r][2], acc[r][3]);
      float4 o1 = make_float4(acc[r][4], acc[r][5], acc[r][6], acc[r][7]);
      *(float4*)(feat + (size_t)n*HD + tx*8)     = o0;
      *(float4*)(feat + (size_t)n*HD + tx*8 + 4) = o1;
      if ((tx & 3) == 0){
        elv[n*NHEADS + head] = pl;
        erv[n*NHEADS + head] = pr;
      }
    }
  }
}

// ---------------- edge softmax (per dst node, thread/node) ----------------
__global__ void softmax_kernel(const int* __restrict__ rowptr, const int* __restrict__ srcs,
                               const float* __restrict__ elv, const float* __restrict__ erv,
                               float* __restrict__ a_sorted, float* __restrict__ ssum, int n)
{
  int nd = blockIdx.x*blockDim.x + threadIdx.x;
  if (nd >= n) return;
  int s0 = rowptr[nd], s1 = rowptr[nd+1];
  float4 er4 = *(const float4*)(erv + nd*4);
  float mx = -3.4e38f, my = -3.4e38f, mz = -3.4e38f, mw = -3.4e38f;
  for (int i = s0; i < s1; i++){
    int s = srcs[i];
    float4 el4 = *(const float4*)(elv + s*4);
    float ex = lrelu(el4.x + er4.x), ey = lrelu(el4.y + er4.y);
    float ez = lrelu(el4.z + er4.z), ew = lrelu(el4.w + er4.w);
    mx = fmaxf(mx, ex); my = fmaxf(my, ey); mz = fmaxf(mz, ez); mw = fmaxf(mw, ew);
  }
  float sx = 0.f, sy = 0.f, sz = 0.f, sw = 0.f;
  for (int i = s0; i < s1; i++){
    int s = srcs[i];
    float4 el4 = *(const float4*)(elv + s*4);
    float4 ex;
    ex.x = __expf(lrelu(el4.x + er4.x) - mx);
    ex.y = __expf(lrelu(el4.y + er4.y) - my);
    ex.z = __expf(lrelu(el4.z + er4.z) - mz);
    ex.w = __expf(lrelu(el4.w + er4.w) - mw);
    *(float4*)(a_sorted + (size_t)i*4) = ex;
    sx += ex.x; sy += ex.y; sz += ex.z; sw += ex.w;
  }
  float4 sv; sv.x = sx; sv.y = sy; sv.z = sz; sv.w = sw;
  *(float4*)(ssum + nd*4) = sv;
}

// ---------------- aggregation (wave per dst node, lane = feature) ----------------
__global__ __launch_bounds__(256) void agg_kernel(
    const int* __restrict__ rowptr, const int* __restrict__ srcs,
    const float* __restrict__ a_sorted, const float* __restrict__ feat,
    const float* __restrict__ ssum, float* __restrict__ emb_out, int n)
{
  int wid  = (int)((blockIdx.x*(size_t)blockDim.x + threadIdx.x) >> 6);
  int lane = threadIdx.x & 63;
  if (wid >= n) return;
  int s0 = rowptr[wid], s1 = rowptr[wid+1];
  int h1 = lane >> 5;                       // head for feature `lane` (0/1); +2 for lane+64
  float acc0 = 0.f, acc1 = 0.f;
  for (int i = s0; i < s1; i++){
    int s = srcs[i];
    float4 a4 = *(const float4*)(a_sorted + (size_t)i*4);
    float aA = (h1 == 0) ? a4.x : a4.y;
    float aB = (h1 == 0) ? a4.z : a4.w;
    const float* fr = feat + (size_t)s*HD;
    acc0 += fr[lane]      * aA;
    acc1 += fr[64 + lane] * aB;
  }
  float4 sv = *(const float4*)(ssum + wid*4);
  float sA = (h1 == 0) ? sv.x : sv.y;
  float sB = (h1 == 0) ? sv.z : sv.w;
  float o0 = (s1 > s0) ? elu(acc0 / sA) : 0.f;
  float o1 = (s1 > s0) ? elu(acc1 / sB) : 0.f;
  emb_out[(size_t)wid*384 + lane]      = o0;   // emb_out pre-offset by layer*128
  emb_out[(size_t)wid*384 + 64 + lane] = o1;
}

// ---------------- final projection: emb[N,384] @ Wproj[384,32] ----------------
// GEMM-tiled: 128 rows x 32 cols per block, K chunked by 32, both operands in LDS.
// 256 threads: tx=t&3 owns cols tx*8..+8, ty=t>>2 owns rows {ty, ty+64}.
// Row-stride-64 micro-tiling keeps wave A-reads on 16 consecutive rows
// (stride 36 floats -> 2-way bank alias = free). Each emb row read from
// global exactly once (round-3 proj read each row 32x -> L2-bound, 100us).
__global__ __launch_bounds__(256) void proj_kernel(
    const float* __restrict__ emb, const float* __restrict__ Wp, float* __restrict__ out)
{
  __shared__ float As[PTILE*36];    // 18432 B
  __shared__ float Wl[32*32];       // 4096 B
  int t = threadIdx.x;
  int tx = t & 3, ty = t >> 2;      // ty 0..63
  int rbase = blockIdx.x * PTILE;

  float acc[2][8];
  #pragma unroll
  for (int r = 0; r < 2; r++)
    #pragma unroll
    for (int j = 0; j < 8; j++) acc[r][j] = 0.f;

  for (int kb = 0; kb < 384; kb += 32){
    // stage A: 128 rows x 32 k = 1024 float4, 4 per thread (coverage: 4*256=1024 ✓)
    #pragma unroll
    for (int i = 0; i < 4; i++){
      int idx = i*256 + t;          // float4 index 0..1023
      int row = idx >> 3;           // 0..127
      int kq  = (idx & 7) * 4;      // 0..28
      int gr  = rbase + row;
      float4 v = make_float4(0.f,0.f,0.f,0.f);
      if (gr < NNODES) v = *(const float4*)(emb + (size_t)gr*384 + kb + kq);
      *(float4*)&As[row*36 + kq] = v;
    }
    // stage W chunk: 32 k x 32 c = 256 float4, 1 per thread (coverage: 256 ✓)
    *(float4*)&Wl[t*4] = *(const float4*)(Wp + (size_t)kb*32 + t*4);
    __syncthreads();

    #pragma unroll 8
    for (int k = 0; k < 32; k++){
      float4 b0 = *(const float4*)&Wl[k*32 + tx*8];
      float4 b1 = *(const float4*)&Wl[k*32 + tx*8 + 4];
      #pragma unroll
      for (int r = 0; r < 2; r++){
        float a = As[(ty + 64*r)*36 + k];
        acc[r][0] += a*b0.x; acc[r][1] += a*b0.y;
        acc[r][2] += a*b0.z; acc[r][3] += a*b0.w;
        acc[r][4] += a*b1.x; acc[r][5] += a*b1.y;
        acc[r][6] += a*b1.z; acc[r][7] += a*b1.w;
      }
    }
    __syncthreads();
  }

  #pragma unroll
  for (int r = 0; r < 2; r++){
    int n = rbase + ty + 64*r;
    if (n < NNODES){
      *(float4*)(out + (size_t)n*32 + tx*8)     = make_float4(acc[r][0], acc[r][1], acc[r][2], acc[r][3]);
      *(float4*)(out + (size_t)n*32 + tx*8 + 4) = make_float4(acc[r][4], acc[r][5], acc[r][6], acc[r][7]);
    }
  }
}

// ---------------- launch ----------------
extern "C" void kernel_launch(void* const* d_in, const int* in_sizes, int n_in,
                              void* d_out, int out_size, void* d_ws, size_t ws_size,
                              hipStream_t stream) {
  const float* x    = (const float*)d_in[0];
  const int*   src  = (const int*)d_in[1];
  const int*   dst  = (const int*)d_in[2];
  const float* Ws_[3]  = { (const float*)d_in[3], (const float*)d_in[6], (const float*)d_in[9]  };
  const float* als[3] = { (const float*)d_in[4], (const float*)d_in[7], (const float*)d_in[10] };
  const float* ars[3] = { (const float*)d_in[5], (const float*)d_in[8], (const float*)d_in[11] };
  const float* Wproj  = (const float*)d_in[12];
  float* out = (float*)d_out;

  char* wptr = (char*)d_ws;
  auto alloc = [&](size_t bytes) -> void* {
    void* p = (void*)wptr; wptr += (bytes + 255) & ~(size_t)255; return p;
  };
  int*   deg        = (int*)  alloc((size_t)NNODES*4);
  int*   wcur       = (int*)  alloc((size_t)NNODES*4);
  int*   rowptr     = (int*)  alloc((size_t)(NNODES+1)*4);
  int*   bsum       = (int*)  alloc(256*4);
  int*   src_sorted = (int*)  alloc((size_t)NEDGES*4);
  float* feat       = (float*)alloc((size_t)NNODES*HD*4);
  float* elv        = (float*)alloc((size_t)NNODES*NHEADS*4);
  float* erv        = (float*)alloc((size_t)NNODES*NHEADS*4);
  float* ssum       = (float*)alloc((size_t)NNODES*NHEADS*4);
  float* a_sorted   = (float*)alloc((size_t)NEDGES*NHEADS*4);
  float* emb        = (float*)alloc((size_t)NNODES*384*4);

  const int NB_SCAN = (NNODES + SCAN_T - 1) / SCAN_T;   // 49

  zero_kernel<<<(NNODES+255)/256, 256, 0, stream>>>(deg, wcur, NNODES);
  count_kernel<<<(NEDGES+255)/256, 256, 0, stream>>>(dst, deg, NEDGES);
  scan1_kernel<<<NB_SCAN, SCAN_T, 0, stream>>>(deg, rowptr, bsum, NNODES);
  scan2_kernel<<<1, 64, 0, stream>>>(bsum, rowptr, NB_SCAN, NNODES, NEDGES);
  scan3_kernel<<<NB_SCAN, SCAN_T, 0, stream>>>(rowptr, bsum, NNODES);
  fill_kernel<<<(NEDGES+255)/256, 256, 0, stream>>>(src, dst, rowptr, wcur, src_sorted, NEDGES);

  const float* hin = x;
  int hstride = 128;
  for (int l = 0; l < 3; l++){
    gemm_feat_kernel<<<(NNODES + TILE_R - 1)/TILE_R, 256, 0, stream>>>(
        hin, hstride, Ws_[l], als[l], ars[l], feat, elv, erv);
    softmax_kernel<<<(NNODES+255)/256, 256, 0, stream>>>(rowptr, src_sorted, elv, erv,
                                                         a_sorted, ssum, NNODES);
    agg_kernel<<<(NNODES*64+255)/256, 256, 0, stream>>>(rowptr, src_sorted, a_sorted, feat,
                                                        ssum, emb + (size_t)l*128, NNODES);
    hin = emb + (size_t)l*128;   // output of layer l feeds layer l+1
    hstride = 384;
  }

  proj_kernel<<<(NNODES + PTILE - 1)/PTILE, 256, 0, stream>>>(emb, Wproj, out);
}

// Round 5
// 502.415 us; speedup vs baseline: 1.9216x; 1.3225x over previous
//
#include <hip/hip_runtime.h>
#include <hip/hip_fp16.h>
#include <math.h>

#define NNODES 50000
#define NEDGES 800000
#define HD     128      // H*D
#define NHEADS 4
#define DH     32
#define SCAN_T 1024

#define TILE_R 64       // gemm rows per block
#define KCH    32       // k-chunk
#define AP     36       // padded A-tile k-stride

#define PTILE  128      // proj rows per block

struct alignas(16) Half8 { __half2 a, b, c, d; };

static __device__ __forceinline__ float lrelu(float x){ return x > 0.f ? x : 0.2f*x; }
static __device__ __forceinline__ float elu(float x){ return x > 0.f ? x : __expf(x) - 1.f; }

// ---------------- CSR build ----------------

__global__ void zero_kernel(int* a, int* b, int n){
  int i = blockIdx.x*blockDim.x + threadIdx.x;
  if (i < n){ a[i] = 0; b[i] = 0; }
}

__global__ void count_kernel(const int* __restrict__ dst, int* deg, int e){
  int i = blockIdx.x*blockDim.x + threadIdx.x;
  if (i < e) atomicAdd(&deg[dst[i]], 1);
}

__global__ void scan1_kernel(const int* __restrict__ deg, int* rowptr, int* bsum, int n){
  __shared__ int tmp[SCAN_T];
  int i = blockIdx.x*SCAN_T + threadIdx.x;
  int x = (i < n) ? deg[i] : 0;
  tmp[threadIdx.x] = x;
  __syncthreads();
  for (int off = 1; off < SCAN_T; off <<= 1){
    int v = (threadIdx.x >= off) ? tmp[threadIdx.x - off] : 0;
    __syncthreads();
    tmp[threadIdx.x] += v;
    __syncthreads();
  }
  if (i < n) rowptr[i] = tmp[threadIdx.x] - x;      // exclusive within block
  if (threadIdx.x == SCAN_T-1) bsum[blockIdx.x] = tmp[SCAN_T-1];
}

__global__ void scan2_kernel(int* bsum, int* rowptr, int nb, int n, int e){
  if (blockIdx.x == 0 && threadIdx.x == 0){
    int run = 0;
    for (int b = 0; b < nb; b++){ int t = bsum[b]; bsum[b] = run; run += t; }
    rowptr[n] = e;
  }
}

__global__ void scan3_kernel(int* rowptr, const int* __restrict__ bsum, int n){
  int i = blockIdx.x*SCAN_T + threadIdx.x;
  if (i < n) rowptr[i] += bsum[blockIdx.x];
}

__global__ void fill_kernel(const int* __restrict__ src, const int* __restrict__ dst,
                            const int* __restrict__ rowptr, int* wcur, int* srcs, int e){
  int i = blockIdx.x*blockDim.x + threadIdx.x;
  if (i >= e) return;
  int d = dst[i];
  int p = atomicAdd(&wcur[d], 1);
  srcs[rowptr[d] + p] = src[i];
}

// ---------------- GEMM (h @ W) + el/er epilogue; feat stored fp16 ----------------
__global__ __launch_bounds__(256) void gemm_feat_kernel(
    const float* __restrict__ h, int hstride,
    const float* __restrict__ W, const float* __restrict__ al, const float* __restrict__ ar,
    __half* __restrict__ feat, float* __restrict__ elv, float* __restrict__ erv)
{
  __shared__ float As[TILE_R*AP];   // 9216 B
  __shared__ float Ws[KCH*HD];      // 16384 B
  int t = threadIdx.x;
  int tx = t & 15, ty = t >> 4;
  int rbase = blockIdx.x * TILE_R;

  float acc[4][8];
  #pragma unroll
  for (int r = 0; r < 4; r++)
    #pragma unroll
    for (int j = 0; j < 8; j++) acc[r][j] = 0.f;

  int arow = t >> 2;            // staging: row 0..63
  int akk  = (t & 3) * 8;       // staging: k-offset 0..31 (2 float4)
  int an   = rbase + arow;
  const float* ap = h + (size_t)an*hstride + akk;

  for (int kb = 0; kb < HD; kb += KCH){
    float4 v0, v1;
    if (an < NNODES){
      v0 = *(const float4*)(ap + kb);
      v1 = *(const float4*)(ap + kb + 4);
    } else {
      v0 = make_float4(0.f,0.f,0.f,0.f);
      v1 = v0;
    }
    *(float4*)&As[arow*AP + akk]     = v0;
    *(float4*)&As[arow*AP + akk + 4] = v1;
    // flat-copy the full 4096-float W chunk: 16 floats per thread
    const float* wp = W + (size_t)kb*HD;
    *(float4*)&Ws[t*8]          = *(const float4*)(wp + t*8);
    *(float4*)&Ws[t*8 + 4]      = *(const float4*)(wp + t*8 + 4);
    *(float4*)&Ws[2048 + t*8]     = *(const float4*)(wp + 2048 + t*8);
    *(float4*)&Ws[2048 + t*8 + 4] = *(const float4*)(wp + 2048 + t*8 + 4);
    __syncthreads();

    #pragma unroll 4
    for (int k = 0; k < KCH; k++){
      float4 b0 = *(const float4*)&Ws[k*HD + tx*8];
      float4 b1 = *(const float4*)&Ws[k*HD + tx*8 + 4];
      #pragma unroll
      for (int r = 0; r < 4; r++){
        float a = As[(ty*4 + r)*AP + k];
        acc[r][0] += a*b0.x; acc[r][1] += a*b0.y;
        acc[r][2] += a*b0.z; acc[r][3] += a*b0.w;
        acc[r][4] += a*b1.x; acc[r][5] += a*b1.y;
        acc[r][6] += a*b1.z; acc[r][7] += a*b1.w;
      }
    }
    __syncthreads();
  }

  // epilogue: el/er. cols tx*8..+8 live in head = tx>>2, d-offset (tx&3)*8.
  int head  = tx >> 2;
  int dbase = (tx & 3) * 8;
  float4 al0 = *(const float4*)(al + head*DH + dbase);
  float4 al1 = *(const float4*)(al + head*DH + dbase + 4);
  float4 ar0 = *(const float4*)(ar + head*DH + dbase);
  float4 ar1 = *(const float4*)(ar + head*DH + dbase + 4);

  #pragma unroll
  for (int r = 0; r < 4; r++){
    int n = rbase + ty*4 + r;
    float pl = acc[r][0]*al0.x + acc[r][1]*al0.y + acc[r][2]*al0.z + acc[r][3]*al0.w
             + acc[r][4]*al1.x + acc[r][5]*al1.y + acc[r][6]*al1.z + acc[r][7]*al1.w;
    float pr = acc[r][0]*ar0.x + acc[r][1]*ar0.y + acc[r][2]*ar0.z + acc[r][3]*ar0.w
             + acc[r][4]*ar1.x + acc[r][5]*ar1.y + acc[r][6]*ar1.z + acc[r][7]*ar1.w;
    pl += __shfl_xor(pl, 1); pl += __shfl_xor(pl, 2);
    pr += __shfl_xor(pr, 1); pr += __shfl_xor(pr, 2);
    if (n < NNODES){
      Half8 o;
      o.a = __floats2half2_rn(acc[r][0], acc[r][1]);
      o.b = __floats2half2_rn(acc[r][2], acc[r][3]);
      o.c = __floats2half2_rn(acc[r][4], acc[r][5]);
      o.d = __floats2half2_rn(acc[r][6], acc[r][7]);
      *(Half8*)(feat + (size_t)n*HD + tx*8) = o;
      if ((tx & 3) == 0){
        elv[n*NHEADS + head] = pl;
        erv[n*NHEADS + head] = pr;
      }
    }
  }
}

// ---------------- edge softmax (per dst node, thread/node) ----------------
__global__ void softmax_kernel(const int* __restrict__ rowptr, const int* __restrict__ srcs,
                               const float* __restrict__ elv, const float* __restrict__ erv,
                               float* __restrict__ a_sorted, float* __restrict__ ssum, int n)
{
  int nd = blockIdx.x*blockDim.x + threadIdx.x;
  if (nd >= n) return;
  int s0 = rowptr[nd], s1 = rowptr[nd+1];
  float4 er4 = *(const float4*)(erv + nd*4);
  float mx = -3.4e38f, my = -3.4e38f, mz = -3.4e38f, mw = -3.4e38f;
  for (int i = s0; i < s1; i++){
    int s = srcs[i];
    float4 el4 = *(const float4*)(elv + s*4);
    float ex = lrelu(el4.x + er4.x), ey = lrelu(el4.y + er4.y);
    float ez = lrelu(el4.z + er4.z), ew = lrelu(el4.w + er4.w);
    mx = fmaxf(mx, ex); my = fmaxf(my, ey); mz = fmaxf(mz, ez); mw = fmaxf(mw, ew);
  }
  float sx = 0.f, sy = 0.f, sz = 0.f, sw = 0.f;
  for (int i = s0; i < s1; i++){
    int s = srcs[i];
    float4 el4 = *(const float4*)(elv + s*4);
    float4 ex;
    ex.x = __expf(lrelu(el4.x + er4.x) - mx);
    ex.y = __expf(lrelu(el4.y + er4.y) - my);
    ex.z = __expf(lrelu(el4.z + er4.z) - mz);
    ex.w = __expf(lrelu(el4.w + er4.w) - mw);
    *(float4*)(a_sorted + (size_t)i*4) = ex;
    sx += ex.x; sy += ex.y; sz += ex.z; sw += ex.w;
  }
  float4 sv; sv.x = sx; sv.y = sy; sv.z = sz; sv.w = sw;
  *(float4*)(ssum + nd*4) = sv;
}

// ---------------- aggregation (wave per dst node, quarter-wave per edge) ----------------
// fp16 feat row = 256 B = 16 lanes x 16 B -> 4 edges in flight per wave-iteration.
// Lane layout: q=lane>>4 selects edge i+q, fl=lane&15 selects features fl*8..+8,
// head = fl>>2. Cross-quarter shfl_xor(16,32) reduce; lanes 0..15 normalize+ELU+store.
__global__ __launch_bounds__(256) void agg_kernel(
    const int* __restrict__ rowptr, const int* __restrict__ srcs,
    const float* __restrict__ a_sorted, const __half* __restrict__ feat,
    const float* __restrict__ ssum, float* __restrict__ emb_out, int n)
{
  int wid  = (int)((blockIdx.x*(size_t)blockDim.x + threadIdx.x) >> 6);
  int lane = threadIdx.x & 63;
  if (wid >= n) return;
  int s0 = rowptr[wid], s1 = rowptr[wid+1];
  int q    = lane >> 4;
  int fl   = lane & 15;
  int head = fl >> 2;
  int fo   = fl * 8;

  float acc[8];
  #pragma unroll
  for (int j = 0; j < 8; j++) acc[j] = 0.f;

  #pragma unroll 2
  for (int i = s0; i < s1; i += 4){
    int e = i + q;
    bool v = (e < s1);
    int s = v ? srcs[e] : 0;
    float a = v ? a_sorted[(size_t)e*4 + head] : 0.f;
    Half8 f = *(const Half8*)(feat + (size_t)s*HD + fo);
    float2 f0 = __half22float2(f.a);
    float2 f1 = __half22float2(f.b);
    float2 f2 = __half22float2(f.c);
    float2 f3 = __half22float2(f.d);
    acc[0] += a*f0.x; acc[1] += a*f0.y;
    acc[2] += a*f1.x; acc[3] += a*f1.y;
    acc[4] += a*f2.x; acc[5] += a*f2.y;
    acc[6] += a*f3.x; acc[7] += a*f3.y;
  }

  #pragma unroll
  for (int j = 0; j < 8; j++){
    acc[j] += __shfl_xor(acc[j], 16);
    acc[j] += __shfl_xor(acc[j], 32);
  }

  if (q == 0){
    float inv = (s1 > s0) ? 1.f / ssum[(size_t)wid*4 + head] : 0.f;
    float4 o0, o1;
    o0.x = elu(acc[0]*inv); o0.y = elu(acc[1]*inv);
    o0.z = elu(acc[2]*inv); o0.w = elu(acc[3]*inv);
    o1.x = elu(acc[4]*inv); o1.y = elu(acc[5]*inv);
    o1.z = elu(acc[6]*inv); o1.w = elu(acc[7]*inv);
    *(float4*)(emb_out + (size_t)wid*384 + fo)     = o0;
    *(float4*)(emb_out + (size_t)wid*384 + fo + 4) = o1;
  }
}

// ---------------- final projection: emb[N,384] @ Wproj[384,32] ----------------
__global__ __launch_bounds__(256) void proj_kernel(
    const float* __restrict__ emb, const float* __restrict__ Wp, float* __restrict__ out)
{
  __shared__ float As[PTILE*36];    // 18432 B
  __shared__ float Wl[32*32];       // 4096 B
  int t = threadIdx.x;
  int tx = t & 3, ty = t >> 2;      // ty 0..63
  int rbase = blockIdx.x * PTILE;

  float acc[2][8];
  #pragma unroll
  for (int r = 0; r < 2; r++)
    #pragma unroll
    for (int j = 0; j < 8; j++) acc[r][j] = 0.f;

  for (int kb = 0; kb < 384; kb += 32){
    #pragma unroll
    for (int i = 0; i < 4; i++){
      int idx = i*256 + t;          // float4 index 0..1023
      int row = idx >> 3;           // 0..127
      int kq  = (idx & 7) * 4;      // 0..28
      int gr  = rbase + row;
      float4 v = make_float4(0.f,0.f,0.f,0.f);
      if (gr < NNODES) v = *(const float4*)(emb + (size_t)gr*384 + kb + kq);
      *(float4*)&As[row*36 + kq] = v;
    }
    *(float4*)&Wl[t*4] = *(const float4*)(Wp + (size_t)kb*32 + t*4);
    __syncthreads();

    #pragma unroll 8
    for (int k = 0; k < 32; k++){
      float4 b0 = *(const float4*)&Wl[k*32 + tx*8];
      float4 b1 = *(const float4*)&Wl[k*32 + tx*8 + 4];
      #pragma unroll
      for (int r = 0; r < 2; r++){
        float a = As[(ty + 64*r)*36 + k];
        acc[r][0] += a*b0.x; acc[r][1] += a*b0.y;
        acc[r][2] += a*b0.z; acc[r][3] += a*b0.w;
        acc[r][4] += a*b1.x; acc[r][5] += a*b1.y;
        acc[r][6] += a*b1.z; acc[r][7] += a*b1.w;
      }
    }
    __syncthreads();
  }

  #pragma unroll
  for (int r = 0; r < 2; r++){
    int n = rbase + ty + 64*r;
    if (n < NNODES){
      *(float4*)(out + (size_t)n*32 + tx*8)     = make_float4(acc[r][0], acc[r][1], acc[r][2], acc[r][3]);
      *(float4*)(out + (size_t)n*32 + tx*8 + 4) = make_float4(acc[r][4], acc[r][5], acc[r][6], acc[r][7]);
    }
  }
}

// ---------------- launch ----------------
extern "C" void kernel_launch(void* const* d_in, const int* in_sizes, int n_in,
                              void* d_out, int out_size, void* d_ws, size_t ws_size,
                              hipStream_t stream) {
  const float* x    = (const float*)d_in[0];
  const int*   src  = (const int*)d_in[1];
  const int*   dst  = (const int*)d_in[2];
  const float* Ws_[3]  = { (const float*)d_in[3], (const float*)d_in[6], (const float*)d_in[9]  };
  const float* als[3] = { (const float*)d_in[4], (const float*)d_in[7], (const float*)d_in[10] };
  const float* ars[3] = { (const float*)d_in[5], (const float*)d_in[8], (const float*)d_in[11] };
  const float* Wproj  = (const float*)d_in[12];
  float* out = (float*)d_out;

  char* wptr = (char*)d_ws;
  auto alloc = [&](size_t bytes) -> void* {
    void* p = (void*)wptr; wptr += (bytes + 255) & ~(size_t)255; return p;
  };
  int*    deg        = (int*)   alloc((size_t)NNODES*4);
  int*    wcur       = (int*)   alloc((size_t)NNODES*4);
  int*    rowptr     = (int*)   alloc((size_t)(NNODES+1)*4);
  int*    bsum       = (int*)   alloc(256*4);
  int*    src_sorted = (int*)   alloc((size_t)NEDGES*4);
  __half* feat       = (__half*)alloc((size_t)NNODES*HD*2);
  float*  elv        = (float*) alloc((size_t)NNODES*NHEADS*4);
  float*  erv        = (float*) alloc((size_t)NNODES*NHEADS*4);
  float*  ssum       = (float*) alloc((size_t)NNODES*NHEADS*4);
  float*  a_sorted   = (float*) alloc((size_t)NEDGES*NHEADS*4);
  float*  emb        = (float*) alloc((size_t)NNODES*384*4);

  const int NB_SCAN = (NNODES + SCAN_T - 1) / SCAN_T;   // 49

  zero_kernel<<<(NNODES+255)/256, 256, 0, stream>>>(deg, wcur, NNODES);
  count_kernel<<<(NEDGES+255)/256, 256, 0, stream>>>(dst, deg, NEDGES);
  scan1_kernel<<<NB_SCAN, SCAN_T, 0, stream>>>(deg, rowptr, bsum, NNODES);
  scan2_kernel<<<1, 64, 0, stream>>>(bsum, rowptr, NB_SCAN, NNODES, NEDGES);
  scan3_kernel<<<NB_SCAN, SCAN_T, 0, stream>>>(rowptr, bsum, NNODES);
  fill_kernel<<<(NEDGES+255)/256, 256, 0, stream>>>(src, dst, rowptr, wcur, src_sorted, NEDGES);

  const float* hin = x;
  int hstride = 128;
  for (int l = 0; l < 3; l++){
    gemm_feat_kernel<<<(NNODES + TILE_R - 1)/TILE_R, 256, 0, stream>>>(
        hin, hstride, Ws_[l], als[l], ars[l], feat, elv, erv);
    softmax_kernel<<<(NNODES+255)/256, 256, 0, stream>>>(rowptr, src_sorted, elv, erv,
                                                         a_sorted, ssum, NNODES);
    agg_kernel<<<(NNODES*64+255)/256, 256, 0, stream>>>(rowptr, src_sorted, a_sorted, feat,
                                                        ssum, emb + (size_t)l*128, NNODES);
    hin = emb + (size_t)l*128;   // output of layer l feeds layer l+1
    hstride = 384;
  }

  proj_kernel<<<(NNODES + PTILE - 1)/PTILE, 256, 0, stream>>>(emb, Wproj, out);
}